// Round 1
// baseline (805.017 us; speedup 1.0000x reference)
//
#include <hip/hip_runtime.h>
#include <math.h>

// ---------------------------------------------------------------------------
// HierarchicalTimeAttention on MI355X — single-pass edge processing.
//
// Algebraic plan (all fp32):
//   p    = nf @ (Wq@Wk^T) + bq@Wk^T          [N,128]  (k-GEMM over E is gone)
//   qb_n = nf_n . (Wq bk) + bq.bk            [N]
//   counting-sort edges by src (node_cnt -> scan -> scatter)
//   per node n (one block): stage its edges' t-rows in LDS once,
//     attn_e = (t_e . p[n] + qb[n]) * SCALE ; ex = exp(attn)
//     per-cluster D_c = sum ex, C_c = count   (LDS, block-local, no atomics)
//     scale_e = ex_e / (D_c C_c) ; agg[n] = sum scale_e t_e ; sw[n] = sum_c 1/C_c
//   out = relu( (agg @ (Wv@Wo) + sw * (bv@Wo)) * (1/nne) + bo )
// ---------------------------------------------------------------------------

#define NN 50000
#define NE 600000
#define DD 128
#define NC 8
#define CAP 48              // max staged edges per node (P[cnt>48] ~ e^-33 for Poisson(12));
                            // correct chunked fallback below for cnt > CAP
#define SCALEF 0.08838834764831845f

// ---- workspace element offsets (fp32/int32 units) ----
// zeroed region:
#define OFF_NODECNT  0          // 50000 i32
#define OFF_FILL     50000      // 50000 i32
#define OFF_MASK     100000     // 256 i32 (cluster-usage masks)
#define ZERO_ELEMS   100256
// non-zeroed (fully written each call):
#define OFF_NODEOFF  100352     // 50000 i32
#define OFF_PARTIAL  150352     // 256 i32
#define OFF_BQK      150608     // 128 f32
#define OFF_BVO      150736     // 128 f32
#define OFF_WQBK     150864     // 128 f32
#define OFF_C0       150992     // 1 f32 (pad 16)
#define OFF_WQK      151008     // 16384 f32
#define OFF_WVO      167392     // 16384 f32
#define OFF_QB       183776     // 50000 f32
#define OFF_SORTED   233776     // 600000 i32
#define OFF_SW       833776     // 50000 f32
#define OFF_EXV      883776     // 600000 f32 (fallback path only)
#define OFF_ASSIGN   1483776    // 600000 i32 (fallback path only)
#define OFF_P        2083776    // 6,400,000 f32 (aliased: agg reuses after block reads its row)
// total: 8,483,776 elems = ~33.9 MB

// --- precompute Wqk = Wq@Wk^T, Wvo = Wv@Wo, bqk, bvo, wqbk, c0
//     + (folded) edge-count histogram over src nodes ---
__global__ __launch_bounds__(256) void k_pre_count(
    const float* __restrict__ Wq, const float* __restrict__ bq,
    const float* __restrict__ Wk, const float* __restrict__ bk,
    const float* __restrict__ Wv, const float* __restrict__ bv,
    const float* __restrict__ Wo, const int* __restrict__ ei,
    int* __restrict__ node_cnt,
    float* __restrict__ Wqk, float* __restrict__ bqk,
    float* __restrict__ Wvo, float* __restrict__ bvo,
    float* __restrict__ wqbk, float* __restrict__ c0) {
  int bid = blockIdx.x, t = threadIdx.x;
  if (bid >= 129) {   // edge-count part: no barriers on this path
    long e = (long)(bid - 129) * 256 + t;
    if (e < NE) atomicAdd(&node_cnt[ei[e]], 1);
    return;
  }
  __shared__ float rq[DD], rv[DD];
  int b = bid;
  if (b < DD) {
    if (t < DD) { rq[t] = Wq[b * DD + t]; rv[t] = Wv[b * DD + t]; }
    __syncthreads();
    if (t < DD) {
      float aq = 0.f, av = 0.f;
      for (int j = 0; j < DD; j++) {
        aq += rq[j] * Wk[t * DD + j];   // Wqk[b,t] = Wq row b . Wk row t
        av += rv[j] * Wo[j * DD + t];   // Wvo[b,t] = Wv row b . Wo col t
      }
      Wqk[b * DD + t] = aq;
      Wvo[b * DD + t] = av;
    }
  } else {
    if (t < DD) {
      float a1 = 0.f, a2 = 0.f, a3 = 0.f;
      for (int j = 0; j < DD; j++) {
        a1 += bq[j] * Wk[t * DD + j];
        a2 += bv[j] * Wo[j * DD + t];
        a3 += Wq[t * DD + j] * bk[j];
      }
      bqk[t] = a1; bvo[t] = a2; wqbk[t] = a3;
      if (t == 0) {
        float s = 0.f;
        for (int j = 0; j < DD; j++) s += bq[j] * bk[j];
        *c0 = s;
      }
    }
  }
}

// --- p = nf @ Wqk + bqk ; qb = nf . wqbk + c0 --- (64-row tiles, 256 thr)
__global__ __launch_bounds__(256) void k_p(
    const float* __restrict__ nf, const float* __restrict__ Wqk,
    const float* __restrict__ bqk, const float* __restrict__ wqbk,
    const float* __restrict__ c0p,
    float* __restrict__ p, float* __restrict__ qb) {
  __shared__ float a_lds[64 * DD];
  __shared__ float wb_lds[DD];
  int t = threadIdx.x;
  long row0 = (long)blockIdx.x * 64;
  for (int it = 0; it < 8; it++) {
    int idx = (it * 256 + t) * 4;
    long r = row0 + idx / DD;
    float4 v = {0.f, 0.f, 0.f, 0.f};
    if (r < NN) v = *(const float4*)(nf + r * DD + (idx % DD));
    *(float4*)(a_lds + idx) = v;
  }
  if (t < DD) wb_lds[t] = wqbk[t];
  __syncthreads();
  int cg = t % 32, rg = t / 32;
  int col0 = cg * 4, r0 = rg * 8;
  float acc[8][4]; float qacc[8];
  for (int r = 0; r < 8; r++) { qacc[r] = 0.f; for (int c = 0; c < 4; c++) acc[r][c] = 0.f; }
  for (int k = 0; k < DD; k++) {
    float4 b4 = *(const float4*)(Wqk + k * DD + col0);
    float wbk = wb_lds[k];
    for (int r = 0; r < 8; r++) {
      float a = a_lds[(r0 + r) * DD + k];
      acc[r][0] += a * b4.x; acc[r][1] += a * b4.y;
      acc[r][2] += a * b4.z; acc[r][3] += a * b4.w;
      qacc[r] += a * wbk;
    }
  }
  float4 bq4 = *(const float4*)(bqk + col0);
  float c0v = *c0p;
  for (int r = 0; r < 8; r++) {
    long row = row0 + r0 + r;
    if (row < NN) {
      float4 o;
      o.x = acc[r][0] + bq4.x; o.y = acc[r][1] + bq4.y;
      o.z = acc[r][2] + bq4.z; o.w = acc[r][3] + bq4.w;
      *(float4*)(p + row * DD + col0) = o;
      if (cg == 0) qb[row] = qacc[r] + c0v;
    }
  }
}

// --- prefix scan of node_cnt (3 kernels) ---
__global__ __launch_bounds__(256) void k_scan1(const int* __restrict__ node_cnt,
                                               int* __restrict__ partial) {
  int i = blockIdx.x * 256 + threadIdx.x;
  int v = (i < NN) ? node_cnt[i] : 0;
  for (int o = 1; o < 64; o <<= 1) v += __shfl_xor(v, o);
  __shared__ int wsum[4];
  if ((threadIdx.x & 63) == 0) wsum[threadIdx.x >> 6] = v;
  __syncthreads();
  if (threadIdx.x == 0) partial[blockIdx.x] = wsum[0] + wsum[1] + wsum[2] + wsum[3];
}

__global__ __launch_bounds__(256) void k_scan2(int* __restrict__ partial) {
  __shared__ int s[256];
  int t = threadIdx.x;
  int v = (t < 196) ? partial[t] : 0;
  s[t] = v;
  __syncthreads();
  for (int o = 1; o < 256; o <<= 1) {
    int add = (t >= o) ? s[t - o] : 0;
    __syncthreads();
    s[t] += add;
    __syncthreads();
  }
  if (t < 196) partial[t] = s[t] - v;  // exclusive
}

__global__ __launch_bounds__(256) void k_scan3(const int* __restrict__ node_cnt,
                                               const int* __restrict__ partial,
                                               int* __restrict__ node_off) {
  __shared__ int s[256];
  int t = threadIdx.x;
  int i = blockIdx.x * 256 + t;
  int v = (i < NN) ? node_cnt[i] : 0;
  s[t] = v;
  __syncthreads();
  for (int o = 1; o < 256; o <<= 1) {
    int add = (t >= o) ? s[t - o] : 0;
    __syncthreads();
    s[t] += add;
    __syncthreads();
  }
  if (i < NN) node_off[i] = partial[blockIdx.x] + s[t] - v;
}

// --- counting-sort scatter of edge ids by src ---
__global__ __launch_bounds__(256) void k_scatter(const int* __restrict__ ei,
                                                 const int* __restrict__ node_off,
                                                 int* __restrict__ fill,
                                                 int* __restrict__ sorted) {
  long e = (long)blockIdx.x * 256 + threadIdx.x;
  if (e < NE) {
    int s = ei[e];
    int pos = node_off[s] + atomicAdd(&fill[s], 1);
    sorted[pos] = (int)e;
  }
}

// --- sim/attn for one staged edge slot (4 lanes/edge). valid result on j==0. ---
__device__ __forceinline__ void sim_attn_edge(
    const float* t_lds, const float* ce_lds, const float* p_lds, float qbv,
    int el, int j, float& ex_out, int& bc_out) {
  const float* trow = t_lds + el * DD;
  int sw8 = el & 7;
  float4 tv[8];
  for (int i = 0; i < 8; i++)
    tv[i] = *(const float4*)(trow + ((i * 4 + j) ^ sw8) * 4);   // de-swizzle
  float sims[NC];
  for (int c = 0; c < NC; c++) {
    const float* cr = ce_lds + c * DD;
    float s = 0.f;
    for (int i = 0; i < 8; i++) {
      float4 cv = *(const float4*)(cr + (i * 4 + j) * 4);
      s += tv[i].x * cv.x + tv[i].y * cv.y + tv[i].z * cv.z + tv[i].w * cv.w;
    }
    sims[c] = s;
  }
  float a = 0.f;
  for (int i = 0; i < 8; i++) {
    float4 pv = *(const float4*)(p_lds + (i * 4 + j) * 4);
    a += tv[i].x * pv.x + tv[i].y * pv.y + tv[i].z * pv.z + tv[i].w * pv.w;
  }
  for (int c = 0; c < NC; c++) {
    sims[c] += __shfl_xor(sims[c], 1);
    sims[c] += __shfl_xor(sims[c], 2);
  }
  a += __shfl_xor(a, 1);
  a += __shfl_xor(a, 2);
  float best = sims[0]; int bc = 0;
  for (int c = 1; c < NC; c++) if (sims[c] > best) { best = sims[c]; bc = c; }
  ex_out = expf((a + qbv) * SCALEF);
  bc_out = bc;
}

// --- fused per-node edge pass: stage t-rows once, block-local softmax, agg ---
// one block per node; t_lds rows XOR-swizzled at float4 granularity to break
// the 512B-row-stride bank-conflict pattern on both read phases.
__global__ __launch_bounds__(256) void k_fused(
    const float* __restrict__ tf, const int* __restrict__ sorted,
    const int* __restrict__ node_off, const int* __restrict__ node_cnt,
    const float* __restrict__ ce, const float* __restrict__ p,
    const float* __restrict__ qb,
    float* __restrict__ exv_g, int* __restrict__ assign_g,
    int* __restrict__ maskArr,
    float* __restrict__ agg, float* __restrict__ sw) {
  __shared__ float t_lds[CAP * DD];     // 24.0 KB
  __shared__ float ce_lds[NC * DD];     // 4 KB
  __shared__ float p_lds[DD];
  __shared__ float team_lds[DD];
  __shared__ float exf[CAP];
  __shared__ float scl[CAP];
  __shared__ int   cli[CAP];
  __shared__ int   eidx[CAP];
  __shared__ float D_sh[NC];
  __shared__ int   C_sh[NC];
  __shared__ float qb_sh;

  int n = blockIdx.x;
  int t = threadIdx.x;
  int off = node_off[n], cnt = node_cnt[n];

  if (cnt == 0) {   // empty node: means are 0 -> agg=0, sw=0 (no barriers hit)
    if (t < 32) {
      float4 z = {0.f, 0.f, 0.f, 0.f};
      *(float4*)(agg + (long)n * DD + t * 4) = z;
    }
    if (t == 0) sw[n] = 0.f;
    return;
  }

  *(float4*)(ce_lds + t * 4) = *(const float4*)(ce + t * 4);   // 8*128 = 256*4
  if (t < 32) *(float4*)(p_lds + t * 4) = *(const float4*)(p + (long)n * DD + t * 4);
  if (t < NC) { D_sh[t] = 0.f; C_sh[t] = 0; }
  if (t == 0) qb_sh = qb[n];

  int el = t >> 2, j = t & 3;
  int d = t & 127, team = t >> 7;
  float aggacc = 0.f;

  if (cnt <= CAP) {
    // ---------------- common path: whole node resident ----------------
    if (t < cnt) eidx[t] = sorted[off + t];
    __syncthreads();
    int total4 = cnt * 32;
    for (int i = t; i < total4; i += 256) {
      int e_i = i >> 5, d4 = i & 31;
      *(float4*)(t_lds + e_i * DD + (d4 ^ (e_i & 7)) * 4) =
          *(const float4*)(tf + (long)eidx[e_i] * DD + d4 * 4);
    }
    __syncthreads();
    if (el < cnt) {
      float ex; int bc;
      sim_attn_edge(t_lds, ce_lds, p_lds, qb_sh, el, j, ex, bc);
      if (j == 0) {
        exf[el] = ex; cli[el] = bc;
        atomicAdd(&D_sh[bc], ex);
        atomicAdd(&C_sh[bc], 1);
      }
    }
    __syncthreads();
    if (t < cnt) scl[t] = exf[t] / (D_sh[cli[t]] * (float)C_sh[cli[t]]);
    if (t == 0) {
      int m = 0; float s = 0.f;
      for (int c = 0; c < NC; c++)
        if (C_sh[c] > 0) { m |= 1 << c; s += 1.0f / (float)C_sh[c]; }
      atomicOr(&maskArr[n & 255], m);
      sw[n] = s;   // sum over e of scale_e == sum over used c of 1/C_c
    }
    __syncthreads();
    for (int e = team; e < cnt; e += 2)
      aggacc += scl[e] * t_lds[e * DD + (((d >> 2) ^ (e & 7)) << 2) + (d & 3)];
  } else {
    // ---------------- rare fallback: chunked two-phase ----------------
    int nchunk = (cnt + CAP - 1) / CAP;
    for (int ch = 0; ch < nchunk; ch++) {
      int base = ch * CAP;
      int m = cnt - base; if (m > CAP) m = CAP;
      __syncthreads();
      if (t < m) eidx[t] = sorted[off + base + t];
      __syncthreads();
      int total4 = m * 32;
      for (int i = t; i < total4; i += 256) {
        int e_i = i >> 5, d4 = i & 31;
        *(float4*)(t_lds + e_i * DD + (d4 ^ (e_i & 7)) * 4) =
            *(const float4*)(tf + (long)eidx[e_i] * DD + d4 * 4);
      }
      __syncthreads();
      if (el < m) {
        float ex; int bc;
        sim_attn_edge(t_lds, ce_lds, p_lds, qb_sh, el, j, ex, bc);
        if (j == 0) {
          exv_g[off + base + el] = ex;
          assign_g[off + base + el] = bc;
          atomicAdd(&D_sh[bc], ex);
          atomicAdd(&C_sh[bc], 1);
        }
      }
    }
    __syncthreads();
    if (t == 0) {
      int m = 0; float s = 0.f;
      for (int c = 0; c < NC; c++)
        if (C_sh[c] > 0) { m |= 1 << c; s += 1.0f / (float)C_sh[c]; }
      atomicOr(&maskArr[n & 255], m);
      sw[n] = s;
    }
    for (int ch = 0; ch < nchunk; ch++) {
      int base = ch * CAP;
      int m = cnt - base; if (m > CAP) m = CAP;
      __syncthreads();
      if (t < m) {
        eidx[t] = sorted[off + base + t];
        int c = assign_g[off + base + t];
        scl[t] = exv_g[off + base + t] / (D_sh[c] * (float)C_sh[c]);
      }
      __syncthreads();
      int total4 = m * 32;
      for (int i = t; i < total4; i += 256) {
        int e_i = i >> 5, d4 = i & 31;
        *(float4*)(t_lds + e_i * DD + (d4 ^ (e_i & 7)) * 4) =
            *(const float4*)(tf + (long)eidx[e_i] * DD + d4 * 4);
      }
      __syncthreads();
      for (int e = team; e < m; e += 2)
        aggacc += scl[e] * t_lds[e * DD + (((d >> 2) ^ (e & 7)) << 2) + (d & 3)];
    }
  }
  // team combine + store (agg row n aliases p row n: p[n] was read above, safe)
  if (team == 1) team_lds[d] = aggacc;
  __syncthreads();
  if (team == 0) agg[(long)n * DD + d] = aggacc + team_lds[d];
}

// --- out = relu((agg @ Wvo + sw*bvo) * inv_nne + bo); inv_nne from maskArr ---
__global__ __launch_bounds__(256) void k_out(
    const float* __restrict__ agg, const float* __restrict__ Wvo,
    const float* __restrict__ bvo, const float* __restrict__ sw,
    const float* __restrict__ bo, const int* __restrict__ maskArr,
    float* __restrict__ out) {
  __shared__ float a_lds[64 * DD];
  __shared__ float sw_lds[64];
  __shared__ int morw[4];
  int t = threadIdx.x;
  int mv = maskArr[t];
  for (int o = 1; o < 64; o <<= 1) mv |= __shfl_xor(mv, o);
  if ((t & 63) == 0) morw[t >> 6] = mv;
  long row0 = (long)blockIdx.x * 64;
  for (int it = 0; it < 8; it++) {
    int idx = (it * 256 + t) * 4;
    long r = row0 + idx / DD;
    float4 v = {0.f, 0.f, 0.f, 0.f};
    if (r < NN) v = *(const float4*)(agg + r * DD + (idx % DD));
    *(float4*)(a_lds + idx) = v;
  }
  if (t < 64) {
    long r = row0 + t;
    sw_lds[t] = (r < NN) ? sw[r] : 0.f;
  }
  __syncthreads();
  int full = morw[0] | morw[1] | morw[2] | morw[3];
  int nne = __popc(full); if (nne == 0) nne = 1;
  float inv = 1.0f / (float)nne;
  int cg = t % 32, rg = t / 32;
  int col0 = cg * 4, r0 = rg * 8;
  float acc[8][4];
  for (int r = 0; r < 8; r++) for (int c = 0; c < 4; c++) acc[r][c] = 0.f;
  for (int k = 0; k < DD; k++) {
    float4 b4 = *(const float4*)(Wvo + k * DD + col0);
    for (int r = 0; r < 8; r++) {
      float a = a_lds[(r0 + r) * DD + k];
      acc[r][0] += a * b4.x; acc[r][1] += a * b4.y;
      acc[r][2] += a * b4.z; acc[r][3] += a * b4.w;
    }
  }
  float4 bv4 = *(const float4*)(bvo + col0);
  float4 bo4 = *(const float4*)(bo + col0);
  for (int r = 0; r < 8; r++) {
    long row = row0 + r0 + r;
    if (row < NN) {
      float s = sw_lds[r0 + r];
      float4 o;
      o.x = fmaxf((acc[r][0] + s * bv4.x) * inv + bo4.x, 0.f);
      o.y = fmaxf((acc[r][1] + s * bv4.y) * inv + bo4.y, 0.f);
      o.z = fmaxf((acc[r][2] + s * bv4.z) * inv + bo4.z, 0.f);
      o.w = fmaxf((acc[r][3] + s * bv4.w) * inv + bo4.w, 0.f);
      *(float4*)(out + row * DD + col0) = o;
    }
  }
}

extern "C" void kernel_launch(void* const* d_in, const int* in_sizes, int n_in,
                              void* d_out, int out_size, void* d_ws, size_t ws_size,
                              hipStream_t stream) {
  const float* nf = (const float*)d_in[0];
  const float* tf = (const float*)d_in[1];
  // d_in[2] = context_feat: unused by the reference
  const int*   ei = (const int*)d_in[3];   // row 0 = src
  const float* Wq = (const float*)d_in[4];
  const float* bq = (const float*)d_in[5];
  const float* Wk = (const float*)d_in[6];
  const float* bk = (const float*)d_in[7];
  const float* Wv = (const float*)d_in[8];
  const float* bv = (const float*)d_in[9];
  const float* ce = (const float*)d_in[10];
  const float* Wo = (const float*)d_in[11];
  const float* bo = (const float*)d_in[12];
  float* out = (float*)d_out;

  float* ws  = (float*)d_ws;
  int*   node_cnt = (int*)(ws + OFF_NODECNT);
  int*   fill     = (int*)(ws + OFF_FILL);
  int*   maskArr  = (int*)(ws + OFF_MASK);
  int*   node_off = (int*)(ws + OFF_NODEOFF);
  int*   partial  = (int*)(ws + OFF_PARTIAL);
  float* bqk      = ws + OFF_BQK;
  float* bvo      = ws + OFF_BVO;
  float* wqbk     = ws + OFF_WQBK;
  float* c0       = ws + OFF_C0;
  float* Wqk      = ws + OFF_WQK;
  float* Wvo      = ws + OFF_WVO;
  float* qb       = ws + OFF_QB;
  int*   sorted   = (int*)(ws + OFF_SORTED);
  float* sw       = ws + OFF_SW;
  float* exv      = ws + OFF_EXV;
  int*   assign   = (int*)(ws + OFF_ASSIGN);
  float* p        = ws + OFF_P;   // [N,128]
  float* agg      = ws + OFF_P;   // aliased: block n reads p[n] before writing agg[n]

  hipMemsetAsync(d_ws, 0, (size_t)ZERO_ELEMS * 4, stream);

  k_pre_count<<<129 + (NE + 255) / 256, 256, 0, stream>>>(
      Wq, bq, Wk, bk, Wv, bv, Wo, ei, node_cnt, Wqk, bqk, Wvo, bvo, wqbk, c0);
  k_p<<<(NN + 63) / 64, 256, 0, stream>>>(nf, Wqk, bqk, wqbk, c0, p, qb);
  k_scan1<<<196, 256, 0, stream>>>(node_cnt, partial);
  k_scan2<<<1, 256, 0, stream>>>(partial);
  k_scan3<<<196, 256, 0, stream>>>(node_cnt, partial, node_off);
  k_scatter<<<(NE + 255) / 256, 256, 0, stream>>>(ei, node_off, fill, sorted);
  k_fused<<<NN, 256, 0, stream>>>(tf, sorted, node_off, node_cnt, ce, p, qb,
                                  exv, assign, maskArr, agg, sw);
  k_out<<<(NN + 63) / 64, 256, 0, stream>>>(agg, Wvo, bvo, sw, bo, maskArr, out);
}

// Round 2
// 745.075 us; speedup vs baseline: 1.0805x; 1.0805x over previous
//
#include <hip/hip_runtime.h>
#include <math.h>

// ---------------------------------------------------------------------------
// HierarchicalTimeAttention on MI355X — edge-window fused pass.
//
//   p    = nf @ (Wq@Wk^T) + bq@Wk^T          [N,128]
//   qb_n = nf_n . (Wq bk) + bq.bk            [N]
//   counting-sort edges by src (count -> scan -> scatter, + window bsearch)
//   k_fused2: blocks own 64-edge windows of the sorted edge list; all nodes
//     starting in a window belong to that block. Per 32-edge chunk:
//       Phase A (256 thr = 32 edges x 8 lanes): read t row (global, once),
//         stage to LDS (xor-swizzled), sims vs ce, attn vs p[src], ex=exp,
//         accumulate per-(node,cluster) D,C in LDS (block-local).
//       Phase U (128 thr, race-free: thread d owns column d): serial over
//         chunk edges, U[c][d] += ex*t; on node boundary flush
//         agg[n][d] = sum_c U[c][d]/(D_c*C_c)  (no barriers needed).
//   out = relu( (agg @ (Wv@Wo) + sw * (bv@Wo)) * (1/nne) + bo )
//
// NOTE: dur_us includes ~370us of harness workspace re-poison fills (2x185us,
// 1.2GB) — constant overhead outside our control.
// ---------------------------------------------------------------------------

#define NN 50000
#define NE 600000
#define DD 128
#define NC 8
#define WIN 64              // sorted-edge window per block
#define NWIN 9376           // NE/WIN + 1 (last window catches off==NE empties)
#define NBF  9377           // blockFirst entries (0..NWIN)
#define CHK 32              // edges staged per chunk
#define NLOC 64             // max nodes per sub-range (D/C LDS capacity)
#define SCALEF 0.08838834764831845f

// ---- workspace element offsets (fp32/int32 units) ----
// zeroed region:
#define OFF_NODECNT  0          // 50000 i32
#define OFF_FILL     50000      // 50000 i32
#define OFF_MASK     100000     // 256 i32
#define ZERO_ELEMS   100256
// non-zeroed (fully written each call):
#define OFF_NODEOFF  100352     // 50000 i32
#define OFF_PARTIAL  150352     // 256 i32
#define OFF_BF       150608     // 9377 i32 (pad)
#define OFF_BQK      160000     // 128 f32
#define OFF_BVO      160128     // 128 f32
#define OFF_WQBK     160256     // 128 f32
#define OFF_C0       160384     // 1 f32 (pad 16)
#define OFF_WQK      160400     // 16384 f32
#define OFF_WVO      176784     // 16384 f32
#define OFF_QB       193168     // 50000 f32
#define OFF_SORTED   243168     // 600000 i32
#define OFF_SRCS     843168     // 600000 i32
#define OFF_SW       1443168    // 50000 f32
#define OFF_P        1493168    // 6,400,000 f32 (agg aliases p: row n written only
                                //  by its owner block after all reads of p[n])
// total: 7,893,168 elems = ~31.6 MB

// --- precompute Wqk = Wq@Wk^T, Wvo = Wv@Wo, bqk, bvo, wqbk, c0
//     + (folded) edge-count histogram over src nodes ---
__global__ __launch_bounds__(256) void k_pre_count(
    const float* __restrict__ Wq, const float* __restrict__ bq,
    const float* __restrict__ Wk, const float* __restrict__ bk,
    const float* __restrict__ Wv, const float* __restrict__ bv,
    const float* __restrict__ Wo, const int* __restrict__ ei,
    int* __restrict__ node_cnt,
    float* __restrict__ Wqk, float* __restrict__ bqk,
    float* __restrict__ Wvo, float* __restrict__ bvo,
    float* __restrict__ wqbk, float* __restrict__ c0) {
  int bid = blockIdx.x, t = threadIdx.x;
  if (bid >= 129) {   // edge-count part: no barriers on this path
    long e = (long)(bid - 129) * 256 + t;
    if (e < NE) atomicAdd(&node_cnt[ei[e]], 1);
    return;
  }
  __shared__ float rq[DD], rv[DD];
  int b = bid;
  if (b < DD) {
    if (t < DD) { rq[t] = Wq[b * DD + t]; rv[t] = Wv[b * DD + t]; }
    __syncthreads();
    if (t < DD) {
      float aq = 0.f, av = 0.f;
      for (int j = 0; j < DD; j++) {
        aq += rq[j] * Wk[t * DD + j];   // Wqk[b,t] = Wq row b . Wk row t
        av += rv[j] * Wo[j * DD + t];   // Wvo[b,t] = Wv row b . Wo col t
      }
      Wqk[b * DD + t] = aq;
      Wvo[b * DD + t] = av;
    }
  } else {
    if (t < DD) {
      float a1 = 0.f, a2 = 0.f, a3 = 0.f;
      for (int j = 0; j < DD; j++) {
        a1 += bq[j] * Wk[t * DD + j];
        a2 += bv[j] * Wo[j * DD + t];
        a3 += Wq[t * DD + j] * bk[j];
      }
      bqk[t] = a1; bvo[t] = a2; wqbk[t] = a3;
      if (t == 0) {
        float s = 0.f;
        for (int j = 0; j < DD; j++) s += bq[j] * bk[j];
        *c0 = s;
      }
    }
  }
}

// --- p = nf @ Wqk + bqk ; qb = nf . wqbk + c0 --- (64-row tiles, 256 thr)
__global__ __launch_bounds__(256) void k_p(
    const float* __restrict__ nf, const float* __restrict__ Wqk,
    const float* __restrict__ bqk, const float* __restrict__ wqbk,
    const float* __restrict__ c0p,
    float* __restrict__ p, float* __restrict__ qb) {
  __shared__ float a_lds[64 * DD];
  __shared__ float wb_lds[DD];
  int t = threadIdx.x;
  long row0 = (long)blockIdx.x * 64;
  for (int it = 0; it < 8; it++) {
    int idx = (it * 256 + t) * 4;
    long r = row0 + idx / DD;
    float4 v = {0.f, 0.f, 0.f, 0.f};
    if (r < NN) v = *(const float4*)(nf + r * DD + (idx % DD));
    *(float4*)(a_lds + idx) = v;
  }
  if (t < DD) wb_lds[t] = wqbk[t];
  __syncthreads();
  int cg = t % 32, rg = t / 32;
  int col0 = cg * 4, r0 = rg * 8;
  float acc[8][4]; float qacc[8];
  for (int r = 0; r < 8; r++) { qacc[r] = 0.f; for (int c = 0; c < 4; c++) acc[r][c] = 0.f; }
  for (int k = 0; k < DD; k++) {
    float4 b4 = *(const float4*)(Wqk + k * DD + col0);
    float wbk = wb_lds[k];
    for (int r = 0; r < 8; r++) {
      float a = a_lds[(r0 + r) * DD + k];
      acc[r][0] += a * b4.x; acc[r][1] += a * b4.y;
      acc[r][2] += a * b4.z; acc[r][3] += a * b4.w;
      qacc[r] += a * wbk;
    }
  }
  float4 bq4 = *(const float4*)(bqk + col0);
  float c0v = *c0p;
  for (int r = 0; r < 8; r++) {
    long row = row0 + r0 + r;
    if (row < NN) {
      float4 o;
      o.x = acc[r][0] + bq4.x; o.y = acc[r][1] + bq4.y;
      o.z = acc[r][2] + bq4.z; o.w = acc[r][3] + bq4.w;
      *(float4*)(p + row * DD + col0) = o;
      if (cg == 0) qb[row] = qacc[r] + c0v;
    }
  }
}

// --- prefix scan of node_cnt (3 kernels) ---
__global__ __launch_bounds__(256) void k_scan1(const int* __restrict__ node_cnt,
                                               int* __restrict__ partial) {
  int i = blockIdx.x * 256 + threadIdx.x;
  int v = (i < NN) ? node_cnt[i] : 0;
  for (int o = 1; o < 64; o <<= 1) v += __shfl_xor(v, o);
  __shared__ int wsum[4];
  if ((threadIdx.x & 63) == 0) wsum[threadIdx.x >> 6] = v;
  __syncthreads();
  if (threadIdx.x == 0) partial[blockIdx.x] = wsum[0] + wsum[1] + wsum[2] + wsum[3];
}

__global__ __launch_bounds__(256) void k_scan2(int* __restrict__ partial) {
  __shared__ int s[256];
  int t = threadIdx.x;
  int v = (t < 196) ? partial[t] : 0;
  s[t] = v;
  __syncthreads();
  for (int o = 1; o < 256; o <<= 1) {
    int add = (t >= o) ? s[t - o] : 0;
    __syncthreads();
    s[t] += add;
    __syncthreads();
  }
  if (t < 196) partial[t] = s[t] - v;  // exclusive
}

__global__ __launch_bounds__(256) void k_scan3(const int* __restrict__ node_cnt,
                                               const int* __restrict__ partial,
                                               int* __restrict__ node_off) {
  __shared__ int s[256];
  int t = threadIdx.x;
  int i = blockIdx.x * 256 + t;
  int v = (i < NN) ? node_cnt[i] : 0;
  s[t] = v;
  __syncthreads();
  for (int o = 1; o < 256; o <<= 1) {
    int add = (t >= o) ? s[t - o] : 0;
    __syncthreads();
    s[t] += add;
    __syncthreads();
  }
  if (i < NN) node_off[i] = partial[blockIdx.x] + s[t] - v;
}

// --- counting-sort scatter (+ folded window lower_bound table) ---
#define EDGE_BLKS 2344      // ceil(NE/256)
#define BS_BLKS   37        // ceil(NBF/256)
__global__ __launch_bounds__(256) void k_scatter(const int* __restrict__ ei,
                                                 const int* __restrict__ node_off,
                                                 int* __restrict__ fill,
                                                 int* __restrict__ sorted,
                                                 int* __restrict__ srcs,
                                                 int* __restrict__ blockFirst) {
  int bid = blockIdx.x, t = threadIdx.x;
  if (bid >= EDGE_BLKS) {
    int w = (bid - EDGE_BLKS) * 256 + t;
    if (w < NBF) {
      int v = w * WIN, lo = 0, hi = NN;
      while (lo < hi) { int mid = (lo + hi) >> 1; if (node_off[mid] < v) lo = mid + 1; else hi = mid; }
      blockFirst[w] = lo;   // first n with off[n] >= w*WIN
    }
    return;
  }
  long e = (long)bid * 256 + t;
  if (e < NE) {
    int s = ei[e];
    int pos = node_off[s] + atomicAdd(&fill[s], 1);
    sorted[pos] = (int)e;
    srcs[pos] = s;
  }
}

// --- fused edge pass over 64-edge windows ---
__global__ __launch_bounds__(256) void k_fused2(
    const float* __restrict__ tf, const int* __restrict__ sorted,
    const int* __restrict__ srcs, const int* __restrict__ node_off,
    const int* __restrict__ node_cnt, const int* __restrict__ blockFirst,
    const float* __restrict__ ce, const float* __restrict__ p,
    const float* __restrict__ qb, int* __restrict__ maskArr,
    float* __restrict__ agg, float* __restrict__ sw) {
  __shared__ float ce_lds[NC * DD];     // 4 KB
  __shared__ float t_lds[CHK * DD];     // 16 KB (xor-swizzled float4 slots)
  __shared__ float U_sh[NC * DD];       // 4 KB (thread d owns column d -> race-free)
  __shared__ float D_sh[NLOC * NC];     // 2 KB
  __shared__ int   C_sh[NLOC * NC];     // 2 KB
  __shared__ float exf_sh[CHK];
  __shared__ int   cli_sh[CHK];
  __shared__ int   eidx_sh[CHK];
  __shared__ int   srcs_sh[CHK];
  __shared__ int   cnt0_sh[NLOC];

  int t = threadIdx.x, b = blockIdx.x;
  int fn = blockFirst[b], ln = blockFirst[b + 1] - 1;
  if (fn >= NN || ln < fn) return;   // window owns no node starts

  *(float4*)(ce_lds + t * 4) = *(const float4*)(ce + t * 4);

  int el = t >> 3, j = t & 7;        // Phase A: 32 edges x 8 lanes
  int d = t & 127;                    // Phase U / flush: column ownership
  int msk_acc = 0;

  for (int s0 = fn; s0 <= ln; s0 += NLOC) {
    int e2 = s0 + NLOC - 1; if (e2 > ln) e2 = ln;
    int nN = e2 - s0 + 1;
    int eb = node_off[s0];
    int ee = node_off[e2] + node_cnt[e2];
    for (int i = t; i < NLOC * NC; i += 256) { D_sh[i] = 0.f; C_sh[i] = 0; }
    for (int i = t; i < NC * DD; i += 256) U_sh[i] = 0.f;
    if (t < nN) cnt0_sh[t] = node_cnt[s0 + t];
    __syncthreads();

    // zero empty owned nodes (uniform branch; rows disjoint from any p reads)
    for (int n = 0; n < nN; n++) {
      if (cnt0_sh[n] == 0) {
        if (t < DD) agg[(long)(s0 + n) * DD + t] = 0.f;
        if (t == 0) sw[s0 + n] = 0.f;
      }
    }

    int cur = -1;
    auto do_flush = [&](int node) {   // barrier-free: only own LDS columns read
      int l = (node - s0) * NC;
      if (t < DD) {
        float acc = 0.f;
        #pragma unroll
        for (int c = 0; c < NC; c++) {
          int cc = C_sh[l + c];
          if (cc > 0)
            acc += U_sh[c * DD + d] * __builtin_amdgcn_rcpf(D_sh[l + c] * (float)cc);
          U_sh[c * DD + d] = 0.f;
        }
        agg[(long)node * DD + d] = acc;
      }
      if (t == 0) {
        float ssw = 0.f; int mk = 0;
        #pragma unroll
        for (int c = 0; c < NC; c++) {
          int cc = C_sh[l + c];
          if (cc > 0) { mk |= 1 << c; ssw += __builtin_amdgcn_rcpf((float)cc); }
        }
        sw[node] = ssw; msk_acc |= mk;
      }
    };

    for (int c0 = eb; c0 < ee; c0 += CHK) {
      int m = ee - c0; if (m > CHK) m = CHK;
      if (t < m) { eidx_sh[t] = sorted[c0 + t]; srcs_sh[t] = srcs[c0 + t]; }
      __syncthreads();

      // ---- Phase A ----
      if (el < m) {
        long eid = eidx_sh[el];
        int src = srcs_sh[el];
        const float* trow = tf + eid * DD;
        const float* prow = p + (long)src * DD;
        float4 tv[4];
        #pragma unroll
        for (int i = 0; i < 4; i++) tv[i] = *(const float4*)(trow + (i * 8 + j) * 4);
        int sw8 = el & 7;
        #pragma unroll
        for (int i = 0; i < 4; i++)
          *(float4*)(t_lds + el * DD + (((i * 8 + j) ^ sw8) << 2)) = tv[i];
        float a = 0.f;
        #pragma unroll
        for (int i = 0; i < 4; i++) {
          float4 pv = *(const float4*)(prow + (i * 8 + j) * 4);
          a += tv[i].x * pv.x + tv[i].y * pv.y + tv[i].z * pv.z + tv[i].w * pv.w;
        }
        float sims[NC];
        #pragma unroll
        for (int c = 0; c < NC; c++) {
          const float* cr = ce_lds + c * DD;
          float sacc = 0.f;
          #pragma unroll
          for (int i = 0; i < 4; i++) {
            float4 cv = *(const float4*)(cr + (i * 8 + j) * 4);
            sacc += tv[i].x * cv.x + tv[i].y * cv.y + tv[i].z * cv.z + tv[i].w * cv.w;
          }
          sims[c] = sacc;
        }
        #pragma unroll
        for (int c = 0; c < NC; c++) {
          sims[c] += __shfl_xor(sims[c], 1);
          sims[c] += __shfl_xor(sims[c], 2);
          sims[c] += __shfl_xor(sims[c], 4);
        }
        a += __shfl_xor(a, 1);
        a += __shfl_xor(a, 2);
        a += __shfl_xor(a, 4);
        if (j == 0) {
          float best = sims[0]; int bc = 0;
          #pragma unroll
          for (int c = 1; c < NC; c++) if (sims[c] > best) { best = sims[c]; bc = c; }
          float ex = expf((a + qb[src]) * SCALEF);
          exf_sh[el] = ex; cli_sh[el] = bc;
          int l = (src - s0) * NC + bc;
          atomicAdd(&D_sh[l], ex);
          atomicAdd(&C_sh[l], 1);
        }
      }
      __syncthreads();

      // ---- Phase U: serial over chunk edges; uniform boundary flushes ----
      for (int ii = 0; ii < m; ii++) {
        int sv = srcs_sh[ii];
        if (sv != cur) {
          if (cur >= 0) do_flush(cur);
          cur = sv;
        }
        if (t < DD) {
          int c = cli_sh[ii];
          float tval = t_lds[ii * DD + ((((d >> 2) ^ (ii & 7)) << 2) | (d & 3))];
          U_sh[c * DD + d] += exf_sh[ii] * tval;
        }
      }
      __syncthreads();   // t_lds/exf reuse next chunk; D adds next chunk
    }
    if (cur >= 0) do_flush(cur);
    __syncthreads();     // D/C/U re-init next sub-range
  }
  if (t == 0 && msk_acc) atomicOr(&maskArr[b & 255], msk_acc);
}

// --- out = relu((agg @ Wvo + sw*bvo) * inv_nne + bo); inv_nne from maskArr ---
__global__ __launch_bounds__(256) void k_out(
    const float* __restrict__ agg, const float* __restrict__ Wvo,
    const float* __restrict__ bvo, const float* __restrict__ sw,
    const float* __restrict__ bo, const int* __restrict__ maskArr,
    float* __restrict__ out) {
  __shared__ float a_lds[64 * DD];
  __shared__ float sw_lds[64];
  __shared__ int morw[4];
  int t = threadIdx.x;
  int mv = maskArr[t];
  for (int o = 1; o < 64; o <<= 1) mv |= __shfl_xor(mv, o);
  if ((t & 63) == 0) morw[t >> 6] = mv;
  long row0 = (long)blockIdx.x * 64;
  for (int it = 0; it < 8; it++) {
    int idx = (it * 256 + t) * 4;
    long r = row0 + idx / DD;
    float4 v = {0.f, 0.f, 0.f, 0.f};
    if (r < NN) v = *(const float4*)(agg + r * DD + (idx % DD));
    *(float4*)(a_lds + idx) = v;
  }
  if (t < 64) {
    long r = row0 + t;
    sw_lds[t] = (r < NN) ? sw[r] : 0.f;
  }
  __syncthreads();
  int full = morw[0] | morw[1] | morw[2] | morw[3];
  int nne = __popc(full); if (nne == 0) nne = 1;
  float inv = 1.0f / (float)nne;
  int cg = t % 32, rg = t / 32;
  int col0 = cg * 4, r0 = rg * 8;
  float acc[8][4];
  for (int r = 0; r < 8; r++) for (int c = 0; c < 4; c++) acc[r][c] = 0.f;
  for (int k = 0; k < DD; k++) {
    float4 b4 = *(const float4*)(Wvo + k * DD + col0);
    for (int r = 0; r < 8; r++) {
      float a = a_lds[(r0 + r) * DD + k];
      acc[r][0] += a * b4.x; acc[r][1] += a * b4.y;
      acc[r][2] += a * b4.z; acc[r][3] += a * b4.w;
    }
  }
  float4 bv4 = *(const float4*)(bvo + col0);
  float4 bo4 = *(const float4*)(bo + col0);
  for (int r = 0; r < 8; r++) {
    long row = row0 + r0 + r;
    if (row < NN) {
      float s = sw_lds[r0 + r];
      float4 o;
      o.x = fmaxf((acc[r][0] + s * bv4.x) * inv + bo4.x, 0.f);
      o.y = fmaxf((acc[r][1] + s * bv4.y) * inv + bo4.y, 0.f);
      o.z = fmaxf((acc[r][2] + s * bv4.z) * inv + bo4.z, 0.f);
      o.w = fmaxf((acc[r][3] + s * bv4.w) * inv + bo4.w, 0.f);
      *(float4*)(out + row * DD + col0) = o;
    }
  }
}

extern "C" void kernel_launch(void* const* d_in, const int* in_sizes, int n_in,
                              void* d_out, int out_size, void* d_ws, size_t ws_size,
                              hipStream_t stream) {
  const float* nf = (const float*)d_in[0];
  const float* tf = (const float*)d_in[1];
  // d_in[2] = context_feat: unused by the reference
  const int*   ei = (const int*)d_in[3];   // row 0 = src
  const float* Wq = (const float*)d_in[4];
  const float* bq = (const float*)d_in[5];
  const float* Wk = (const float*)d_in[6];
  const float* bk = (const float*)d_in[7];
  const float* Wv = (const float*)d_in[8];
  const float* bv = (const float*)d_in[9];
  const float* ce = (const float*)d_in[10];
  const float* Wo = (const float*)d_in[11];
  const float* bo = (const float*)d_in[12];
  float* out = (float*)d_out;

  float* ws  = (float*)d_ws;
  int*   node_cnt = (int*)(ws + OFF_NODECNT);
  int*   fill     = (int*)(ws + OFF_FILL);
  int*   maskArr  = (int*)(ws + OFF_MASK);
  int*   node_off = (int*)(ws + OFF_NODEOFF);
  int*   partial  = (int*)(ws + OFF_PARTIAL);
  int*   blockFirst = (int*)(ws + OFF_BF);
  float* bqk      = ws + OFF_BQK;
  float* bvo      = ws + OFF_BVO;
  float* wqbk     = ws + OFF_WQBK;
  float* c0       = ws + OFF_C0;
  float* Wqk      = ws + OFF_WQK;
  float* Wvo      = ws + OFF_WVO;
  float* qb       = ws + OFF_QB;
  int*   sorted   = (int*)(ws + OFF_SORTED);
  int*   srcs     = (int*)(ws + OFF_SRCS);
  float* sw       = ws + OFF_SW;
  float* p        = ws + OFF_P;   // [N,128]
  float* agg      = ws + OFF_P;   // aliased (ownership-safe)

  hipMemsetAsync(d_ws, 0, (size_t)ZERO_ELEMS * 4, stream);

  k_pre_count<<<129 + EDGE_BLKS, 256, 0, stream>>>(
      Wq, bq, Wk, bk, Wv, bv, Wo, ei, node_cnt, Wqk, bqk, Wvo, bvo, wqbk, c0);
  k_p<<<(NN + 63) / 64, 256, 0, stream>>>(nf, Wqk, bqk, wqbk, c0, p, qb);
  k_scan1<<<196, 256, 0, stream>>>(node_cnt, partial);
  k_scan2<<<1, 256, 0, stream>>>(partial);
  k_scan3<<<196, 256, 0, stream>>>(node_cnt, partial, node_off);
  k_scatter<<<EDGE_BLKS + BS_BLKS, 256, 0, stream>>>(ei, node_off, fill, sorted,
                                                     srcs, blockFirst);
  k_fused2<<<NWIN, 256, 0, stream>>>(tf, sorted, srcs, node_off, node_cnt,
                                     blockFirst, ce, p, qb, maskArr, agg, sw);
  k_out<<<(NN + 63) / 64, 256, 0, stream>>>(agg, Wvo, bvo, sw, bo, maskArr, out);
}

// Round 3
// 688.482 us; speedup vs baseline: 1.1693x; 1.0822x over previous
//
#include <hip/hip_runtime.h>
#include <math.h>

// ---------------------------------------------------------------------------
// HierarchicalTimeAttention on MI355X — resident-span fused edge pass.
//
//   p    = nf @ (Wq@Wk^T) + bq@Wk^T          [N,128]
//   qb_n = nf_n . (Wq bk) + bq.bk            [N]
//   counting-sort edges by src (count -> scan -> scatter, + window bsearch)
//   k_fused3: block owns nodes starting in its 64-edge window. Greedy: take
//     node prefix whose edge span fits EC=84 LDS rows, then
//       Phase A (64 edges x 4 lanes): t row global->regs, stage to LDS
//         (xor-swizzled), attn dot vs p[src], sims vs ce, 4-lane reduce,
//         ex=exp, LDS-atomic per-(node,cluster) D,C.   [all 256 thr busy]
//       Phase B: scl[e] = ex_e * rcp(D_c*C_c)          [parallel over span]
//       Phase C: 4 teams x 64 thr x float2 cols: register-accumulated
//         segmented sum over each node's edges -> agg[n]; sw[n]=sum 1/C_c.
//     No LDS accumulator round-trips, no per-node flush chains.
//   out = relu( (agg @ (Wv@Wo) + sw * (bv@Wo)) * (1/nne) + bo )
//
// NOTE: dur_us includes ~370us of harness workspace re-poison fills (2x185us,
// 1.2GB) — constant overhead outside our control.
// ---------------------------------------------------------------------------

#define NN 50000
#define NE 600000
#define DD 128
#define NC 8
#define WIN 64              // sorted-edge window per block
#define NWIN 9376           // NE/WIN + 1 (last window catches off==NE empties)
#define NBF  9377           // blockFirst entries (0..NWIN)
#define EC 84               // resident edge rows (span = 63 + deg(last) fits if deg<=21)
#define NLOC 32             // max nodes per greedy sub-range
#define SCALEF 0.08838834764831845f

// ---- workspace element offsets (fp32/int32 units) ----
// zeroed region:
#define OFF_NODECNT  0          // 50000 i32
#define OFF_FILL     50000      // 50000 i32
#define OFF_MASK     100000     // 256 i32
#define ZERO_ELEMS   100256
// non-zeroed (fully written each call):
#define OFF_NODEOFF  100352     // 50000 i32
#define OFF_PARTIAL  150352     // 256 i32
#define OFF_BF       150608     // 9377 i32 (pad)
#define OFF_BQK      160000     // 128 f32
#define OFF_BVO      160128     // 128 f32
#define OFF_WQBK     160256     // 128 f32
#define OFF_C0       160384     // 1 f32 (pad 16)
#define OFF_WQK      160400     // 16384 f32
#define OFF_WVO      176784     // 16384 f32
#define OFF_QB       193168     // 50000 f32
#define OFF_SORTED   243168     // 600000 i32
#define OFF_SRCS     843168     // 600000 i32
#define OFF_SW       1443168    // 50000 f32
#define OFF_P        1493168    // 6,400,000 f32 (agg aliases p: row n written only
                                //  by its owner block after all reads of p[n])
// total: 7,893,168 elems = ~31.6 MB

// --- precompute Wqk = Wq@Wk^T, Wvo = Wv@Wo, bqk, bvo, wqbk, c0
//     + (folded) edge-count histogram over src nodes ---
__global__ __launch_bounds__(256) void k_pre_count(
    const float* __restrict__ Wq, const float* __restrict__ bq,
    const float* __restrict__ Wk, const float* __restrict__ bk,
    const float* __restrict__ Wv, const float* __restrict__ bv,
    const float* __restrict__ Wo, const int* __restrict__ ei,
    int* __restrict__ node_cnt,
    float* __restrict__ Wqk, float* __restrict__ bqk,
    float* __restrict__ Wvo, float* __restrict__ bvo,
    float* __restrict__ wqbk, float* __restrict__ c0) {
  int bid = blockIdx.x, t = threadIdx.x;
  if (bid >= 129) {   // edge-count part: no barriers on this path
    long e = (long)(bid - 129) * 256 + t;
    if (e < NE) atomicAdd(&node_cnt[ei[e]], 1);
    return;
  }
  __shared__ float rq[DD], rv[DD];
  int b = bid;
  if (b < DD) {
    if (t < DD) { rq[t] = Wq[b * DD + t]; rv[t] = Wv[b * DD + t]; }
    __syncthreads();
    if (t < DD) {
      float aq = 0.f, av = 0.f;
      for (int j = 0; j < DD; j++) {
        aq += rq[j] * Wk[t * DD + j];   // Wqk[b,t] = Wq row b . Wk row t
        av += rv[j] * Wo[j * DD + t];   // Wvo[b,t] = Wv row b . Wo col t
      }
      Wqk[b * DD + t] = aq;
      Wvo[b * DD + t] = av;
    }
  } else {
    if (t < DD) {
      float a1 = 0.f, a2 = 0.f, a3 = 0.f;
      for (int j = 0; j < DD; j++) {
        a1 += bq[j] * Wk[t * DD + j];
        a2 += bv[j] * Wo[j * DD + t];
        a3 += Wq[t * DD + j] * bk[j];
      }
      bqk[t] = a1; bvo[t] = a2; wqbk[t] = a3;
      if (t == 0) {
        float s = 0.f;
        for (int j = 0; j < DD; j++) s += bq[j] * bk[j];
        *c0 = s;
      }
    }
  }
}

// --- p = nf @ Wqk + bqk ; qb = nf . wqbk + c0 --- (64-row tiles, 256 thr)
__global__ __launch_bounds__(256) void k_p(
    const float* __restrict__ nf, const float* __restrict__ Wqk,
    const float* __restrict__ bqk, const float* __restrict__ wqbk,
    const float* __restrict__ c0p,
    float* __restrict__ p, float* __restrict__ qb) {
  __shared__ float a_lds[64 * DD];
  __shared__ float wb_lds[DD];
  int t = threadIdx.x;
  long row0 = (long)blockIdx.x * 64;
  for (int it = 0; it < 8; it++) {
    int idx = (it * 256 + t) * 4;
    long r = row0 + idx / DD;
    float4 v = {0.f, 0.f, 0.f, 0.f};
    if (r < NN) v = *(const float4*)(nf + r * DD + (idx % DD));
    *(float4*)(a_lds + idx) = v;
  }
  if (t < DD) wb_lds[t] = wqbk[t];
  __syncthreads();
  int cg = t % 32, rg = t / 32;
  int col0 = cg * 4, r0 = rg * 8;
  float acc[8][4]; float qacc[8];
  for (int r = 0; r < 8; r++) { qacc[r] = 0.f; for (int c = 0; c < 4; c++) acc[r][c] = 0.f; }
  for (int k = 0; k < DD; k++) {
    float4 b4 = *(const float4*)(Wqk + k * DD + col0);
    float wbk = wb_lds[k];
    for (int r = 0; r < 8; r++) {
      float a = a_lds[(r0 + r) * DD + k];
      acc[r][0] += a * b4.x; acc[r][1] += a * b4.y;
      acc[r][2] += a * b4.z; acc[r][3] += a * b4.w;
      qacc[r] += a * wbk;
    }
  }
  float4 bq4 = *(const float4*)(bqk + col0);
  float c0v = *c0p;
  for (int r = 0; r < 8; r++) {
    long row = row0 + r0 + r;
    if (row < NN) {
      float4 o;
      o.x = acc[r][0] + bq4.x; o.y = acc[r][1] + bq4.y;
      o.z = acc[r][2] + bq4.z; o.w = acc[r][3] + bq4.w;
      *(float4*)(p + row * DD + col0) = o;
      if (cg == 0) qb[row] = qacc[r] + c0v;
    }
  }
}

// --- prefix scan of node_cnt (3 kernels) ---
__global__ __launch_bounds__(256) void k_scan1(const int* __restrict__ node_cnt,
                                               int* __restrict__ partial) {
  int i = blockIdx.x * 256 + threadIdx.x;
  int v = (i < NN) ? node_cnt[i] : 0;
  for (int o = 1; o < 64; o <<= 1) v += __shfl_xor(v, o);
  __shared__ int wsum[4];
  if ((threadIdx.x & 63) == 0) wsum[threadIdx.x >> 6] = v;
  __syncthreads();
  if (threadIdx.x == 0) partial[blockIdx.x] = wsum[0] + wsum[1] + wsum[2] + wsum[3];
}

__global__ __launch_bounds__(256) void k_scan2(int* __restrict__ partial) {
  __shared__ int s[256];
  int t = threadIdx.x;
  int v = (t < 196) ? partial[t] : 0;
  s[t] = v;
  __syncthreads();
  for (int o = 1; o < 256; o <<= 1) {
    int add = (t >= o) ? s[t - o] : 0;
    __syncthreads();
    s[t] += add;
    __syncthreads();
  }
  if (t < 196) partial[t] = s[t] - v;  // exclusive
}

__global__ __launch_bounds__(256) void k_scan3(const int* __restrict__ node_cnt,
                                               const int* __restrict__ partial,
                                               int* __restrict__ node_off) {
  __shared__ int s[256];
  int t = threadIdx.x;
  int i = blockIdx.x * 256 + t;
  int v = (i < NN) ? node_cnt[i] : 0;
  s[t] = v;
  __syncthreads();
  for (int o = 1; o < 256; o <<= 1) {
    int add = (t >= o) ? s[t - o] : 0;
    __syncthreads();
    s[t] += add;
    __syncthreads();
  }
  if (i < NN) node_off[i] = partial[blockIdx.x] + s[t] - v;
}

// --- counting-sort scatter (+ folded window lower_bound table) ---
#define EDGE_BLKS 2344      // ceil(NE/256)
#define BS_BLKS   37        // ceil(NBF/256)
__global__ __launch_bounds__(256) void k_scatter(const int* __restrict__ ei,
                                                 const int* __restrict__ node_off,
                                                 int* __restrict__ fill,
                                                 int* __restrict__ sorted,
                                                 int* __restrict__ srcs,
                                                 int* __restrict__ blockFirst) {
  int bid = blockIdx.x, t = threadIdx.x;
  if (bid >= EDGE_BLKS) {
    int w = (bid - EDGE_BLKS) * 256 + t;
    if (w < NBF) {
      int v = w * WIN, lo = 0, hi = NN;
      while (lo < hi) { int mid = (lo + hi) >> 1; if (node_off[mid] < v) lo = mid + 1; else hi = mid; }
      blockFirst[w] = lo;   // first n with off[n] >= w*WIN
    }
    return;
  }
  long e = (long)bid * 256 + t;
  if (e < NE) {
    int s = ei[e];
    int pos = node_off[s] + atomicAdd(&fill[s], 1);
    sorted[pos] = (int)e;
    srcs[pos] = s;
  }
}

// --- Phase A worker: one edge, 4 lanes (j=0..3), lane j owns bytes [j*128,(j+1)*128)
__device__ __forceinline__ void phase_a(
    const float* __restrict__ tf, const float* __restrict__ p,
    const float* __restrict__ qb,
    const float* ce_lds, float* t_lds, float* exf_sh, int* cli_sh,
    float* D_sh, int* C_sh,
    int el, int j, int eid, int src, int lnode, bool doStage, bool doDC) {
  const float* trow = tf + (long)eid * DD;
  float4 tv[8];
  #pragma unroll
  for (int i = 0; i < 8; i++) tv[i] = *(const float4*)(trow + (j * 8 + i) * 4);
  if (doStage) {
    int e7 = el & 7;
    #pragma unroll
    for (int i = 0; i < 8; i++)
      *(float4*)(t_lds + el * DD + (((j * 8 + i) ^ e7) << 2)) = tv[i];
  }
  const float* prow = p + (long)src * DD;
  float a = 0.f;
  #pragma unroll
  for (int i = 0; i < 8; i++) {
    float4 pv = *(const float4*)(prow + (j * 8 + i) * 4);
    a += tv[i].x * pv.x + tv[i].y * pv.y + tv[i].z * pv.z + tv[i].w * pv.w;
  }
  float sims[NC];
  #pragma unroll
  for (int c = 0; c < NC; c++) {
    const float* cr = ce_lds + c * DD;
    float s = 0.f;
    #pragma unroll
    for (int i = 0; i < 8; i++) {
      float4 cv = *(const float4*)(cr + (j * 8 + i) * 4);
      s += tv[i].x * cv.x + tv[i].y * cv.y + tv[i].z * cv.z + tv[i].w * cv.w;
    }
    sims[c] = s;
  }
  #pragma unroll
  for (int c = 0; c < NC; c++) {
    sims[c] += __shfl_xor(sims[c], 1);
    sims[c] += __shfl_xor(sims[c], 2);
  }
  a += __shfl_xor(a, 1);
  a += __shfl_xor(a, 2);
  if (j == 0) {
    float best = sims[0]; int bc = 0;
    #pragma unroll
    for (int c = 1; c < NC; c++) if (sims[c] > best) { best = sims[c]; bc = c; }
    float ex = expf((a + qb[src]) * SCALEF);
    exf_sh[el] = ex; cli_sh[el] = bc;
    if (doDC) {
      atomicAdd(&D_sh[lnode * NC + bc], ex);
      atomicAdd(&C_sh[lnode * NC + bc], 1);
    }
  }
}

// --- fused edge pass: resident span, parallel scale, register aggregation ---
__global__ __launch_bounds__(256) void k_fused3(
    const float* __restrict__ tf, const int* __restrict__ sorted,
    const int* __restrict__ srcs, const int* __restrict__ node_off,
    const int* __restrict__ node_cnt, const int* __restrict__ blockFirst,
    const float* __restrict__ ce, const float* __restrict__ p,
    const float* __restrict__ qb, int* __restrict__ maskArr,
    float* __restrict__ agg, float* __restrict__ sw) {
  __shared__ float t_lds[EC * DD];      // 42 KB (xor-swizzled float4 slots)
  __shared__ float ce_lds[NC * DD];     // 4 KB
  __shared__ float exf_sh[EC];
  __shared__ float scl_sh[EC];
  __shared__ int   cli_sh[EC];
  __shared__ int   eidx_sh[EC];
  __shared__ int   srcs_sh[EC];
  __shared__ int   offL_sh[NLOC];
  __shared__ int   cntL_sh[NLOC];
  __shared__ float D_sh[NLOC * NC];     // 1 KB
  __shared__ int   C_sh[NLOC * NC];     // 1 KB
  __shared__ int   ctrl[4];             // 0:nN 1:span 2:eb 3:bigCnt

  int t = threadIdx.x, b = blockIdx.x;
  int fn = blockFirst[b], ln = blockFirst[b + 1] - 1;
  if (fn >= NN || ln < fn) return;   // window owns no node starts

  *(float4*)(ce_lds + t * 4) = *(const float4*)(ce + t * 4);

  int el4 = t >> 2, j4 = t & 3;            // Phase A mapping
  int team = t >> 6, d2 = (t & 63) * 2;    // Phase C: 4 teams x 64 thr x float2
  int msk = 0;

  int s0 = fn;
  while (s0 <= ln) {
    // ---- wave 0: greedy node-prefix pick ----
    if (t < 64) {
      int offv = 0, cntv = 0; bool fit = false;
      if (t < NLOC && s0 + t <= ln) { offv = node_off[s0 + t]; cntv = node_cnt[s0 + t]; }
      int off0 = __shfl(offv, 0);
      if (t < NLOC && s0 + t <= ln) fit = (offv - off0 + cntv) <= EC;
      unsigned long long bm = __ballot(fit);
      int pref = (int)__popcll(bm);        // fit is a monotone prefix
      if (t < pref) { offL_sh[t] = offv - off0; cntL_sh[t] = cntv; }
      if (t == 0) { ctrl[0] = pref; ctrl[2] = off0; ctrl[3] = cntv; }
      if (pref > 0 && t == pref - 1) ctrl[1] = offv - off0 + cntv;  // span
    }
    for (int i = t; i < NLOC * NC; i += 256) { D_sh[i] = 0.f; C_sh[i] = 0; }
    __syncthreads();
    int nN = ctrl[0], eb = ctrl[2];

    if (nN == 0) {
      // ---- pathological single node with > EC edges: chunked two-pass ----
      int cnt = ctrl[3];
      for (int c0 = 0; c0 < cnt; c0 += 64) {        // pass 1: D,C
        int m = cnt - c0; if (m > 64) m = 64;
        if (t < m) eidx_sh[t] = sorted[eb + c0 + t];
        __syncthreads();
        if (el4 < m)
          phase_a(tf, p, qb, ce_lds, t_lds, exf_sh, cli_sh, D_sh, C_sh,
                  el4, j4, eidx_sh[el4], s0, 0, false, true);
        __syncthreads();
      }
      float r0a = 0.f, r1a = 0.f;
      for (int c0 = 0; c0 < cnt; c0 += EC) {        // pass 2: aggregate
        int m = cnt - c0; if (m > EC) m = EC;
        if (t < m) eidx_sh[t] = sorted[eb + c0 + t];
        __syncthreads();
        for (int r0 = 0; r0 < m; r0 += 64) {
          int el = r0 + el4;
          if (el < m)
            phase_a(tf, p, qb, ce_lds, t_lds, exf_sh, cli_sh, D_sh, C_sh,
                    el, j4, eidx_sh[el], s0, 0, true, false);
        }
        __syncthreads();
        if (t < m) {
          int c = cli_sh[t];
          scl_sh[t] = exf_sh[t] * __builtin_amdgcn_rcpf(D_sh[c] * (float)C_sh[c]);
        }
        __syncthreads();
        for (int e = team; e < m; e += 4) {
          float s = scl_sh[e];
          const float* tp = t_lds + e * DD + ((((d2 >> 2) ^ (e & 7)) << 2) | (d2 & 3));
          r0a += s * tp[0]; r1a += s * tp[1];
        }
        __syncthreads();
      }
      *(float2*)(t_lds + team * DD + d2) = make_float2(r0a, r1a);  // team combine
      __syncthreads();
      if (team == 0) {
        float s0v = 0.f, s1v = 0.f;
        #pragma unroll
        for (int tm = 0; tm < 4; tm++) {
          s0v += t_lds[tm * DD + d2]; s1v += t_lds[tm * DD + d2 + 1];
        }
        *(float2*)(agg + (long)s0 * DD + d2) = make_float2(s0v, s1v);
      }
      if (t == 0) {
        float ssw = 0.f; int mk = 0;
        #pragma unroll
        for (int c = 0; c < NC; c++) {
          int cc = C_sh[c];
          if (cc > 0) { mk |= 1 << c; ssw += __builtin_amdgcn_rcpf((float)cc); }
        }
        sw[s0] = ssw; msk |= mk;
      }
      __syncthreads();
      s0 += 1;
      continue;
    }

    int span = ctrl[1];
    if (t < span) { eidx_sh[t] = sorted[eb + t]; srcs_sh[t] = srcs[eb + t]; }
    __syncthreads();

    // ---- Phase A: all span edges, 4 lanes each ----
    for (int r0 = 0; r0 < span; r0 += 64) {
      int el = r0 + el4;
      if (el < span) {
        int src = srcs_sh[el];
        phase_a(tf, p, qb, ce_lds, t_lds, exf_sh, cli_sh, D_sh, C_sh,
                el, j4, eidx_sh[el], src, src - s0, true, true);
      }
    }
    __syncthreads();

    // ---- Phase B: parallel scale ----
    if (t < span) {
      int l = (srcs_sh[t] - s0) * NC + cli_sh[t];
      scl_sh[t] = exf_sh[t] * __builtin_amdgcn_rcpf(D_sh[l] * (float)C_sh[l]);
    }
    __syncthreads();

    // ---- Phase C: register-accumulated segmented sums ----
    for (int k = team; k < nN; k += 4) {
      float r0a = 0.f, r1a = 0.f;
      int e1 = offL_sh[k] + cntL_sh[k];
      for (int e = offL_sh[k]; e < e1; e++) {
        float s = scl_sh[e];
        const float* tp = t_lds + e * DD + ((((d2 >> 2) ^ (e & 7)) << 2) | (d2 & 3));
        r0a += s * tp[0]; r1a += s * tp[1];
      }
      long n = s0 + k;
      *(float2*)(agg + n * DD + d2) = make_float2(r0a, r1a);
      if ((t & 63) == 0) {
        float ssw = 0.f; int mk = 0;
        #pragma unroll
        for (int c = 0; c < NC; c++) {
          int cc = C_sh[k * NC + c];
          if (cc > 0) { mk |= 1 << c; ssw += __builtin_amdgcn_rcpf((float)cc); }
        }
        sw[n] = ssw; msk |= mk;
      }
    }
    __syncthreads();
    s0 += nN;
  }
  if (msk) atomicOr(&maskArr[b & 255], msk);
}

// --- out = relu((agg @ Wvo + sw*bvo) * inv_nne + bo); inv_nne from maskArr ---
__global__ __launch_bounds__(256) void k_out(
    const float* __restrict__ agg, const float* __restrict__ Wvo,
    const float* __restrict__ bvo, const float* __restrict__ sw,
    const float* __restrict__ bo, const int* __restrict__ maskArr,
    float* __restrict__ out) {
  __shared__ float a_lds[64 * DD];
  __shared__ float sw_lds[64];
  __shared__ int morw[4];
  int t = threadIdx.x;
  int mv = maskArr[t];
  for (int o = 1; o < 64; o <<= 1) mv |= __shfl_xor(mv, o);
  if ((t & 63) == 0) morw[t >> 6] = mv;
  long row0 = (long)blockIdx.x * 64;
  for (int it = 0; it < 8; it++) {
    int idx = (it * 256 + t) * 4;
    long r = row0 + idx / DD;
    float4 v = {0.f, 0.f, 0.f, 0.f};
    if (r < NN) v = *(const float4*)(agg + r * DD + (idx % DD));
    *(float4*)(a_lds + idx) = v;
  }
  if (t < 64) {
    long r = row0 + t;
    sw_lds[t] = (r < NN) ? sw[r] : 0.f;
  }
  __syncthreads();
  int full = morw[0] | morw[1] | morw[2] | morw[3];
  int nne = __popc(full); if (nne == 0) nne = 1;
  float inv = 1.0f / (float)nne;
  int cg = t % 32, rg = t / 32;
  int col0 = cg * 4, r0 = rg * 8;
  float acc[8][4];
  for (int r = 0; r < 8; r++) for (int c = 0; c < 4; c++) acc[r][c] = 0.f;
  for (int k = 0; k < DD; k++) {
    float4 b4 = *(const float4*)(Wvo + k * DD + col0);
    for (int r = 0; r < 8; r++) {
      float a = a_lds[(r0 + r) * DD + k];
      acc[r][0] += a * b4.x; acc[r][1] += a * b4.y;
      acc[r][2] += a * b4.z; acc[r][3] += a * b4.w;
    }
  }
  float4 bv4 = *(const float4*)(bvo + col0);
  float4 bo4 = *(const float4*)(bo + col0);
  for (int r = 0; r < 8; r++) {
    long row = row0 + r0 + r;
    if (row < NN) {
      float s = sw_lds[r0 + r];
      float4 o;
      o.x = fmaxf((acc[r][0] + s * bv4.x) * inv + bo4.x, 0.f);
      o.y = fmaxf((acc[r][1] + s * bv4.y) * inv + bo4.y, 0.f);
      o.z = fmaxf((acc[r][2] + s * bv4.z) * inv + bo4.z, 0.f);
      o.w = fmaxf((acc[r][3] + s * bv4.w) * inv + bo4.w, 0.f);
      *(float4*)(out + row * DD + col0) = o;
    }
  }
}

extern "C" void kernel_launch(void* const* d_in, const int* in_sizes, int n_in,
                              void* d_out, int out_size, void* d_ws, size_t ws_size,
                              hipStream_t stream) {
  const float* nf = (const float*)d_in[0];
  const float* tf = (const float*)d_in[1];
  // d_in[2] = context_feat: unused by the reference
  const int*   ei = (const int*)d_in[3];   // row 0 = src
  const float* Wq = (const float*)d_in[4];
  const float* bq = (const float*)d_in[5];
  const float* Wk = (const float*)d_in[6];
  const float* bk = (const float*)d_in[7];
  const float* Wv = (const float*)d_in[8];
  const float* bv = (const float*)d_in[9];
  const float* ce = (const float*)d_in[10];
  const float* Wo = (const float*)d_in[11];
  const float* bo = (const float*)d_in[12];
  float* out = (float*)d_out;

  float* ws  = (float*)d_ws;
  int*   node_cnt = (int*)(ws + OFF_NODECNT);
  int*   fill     = (int*)(ws + OFF_FILL);
  int*   maskArr  = (int*)(ws + OFF_MASK);
  int*   node_off = (int*)(ws + OFF_NODEOFF);
  int*   partial  = (int*)(ws + OFF_PARTIAL);
  int*   blockFirst = (int*)(ws + OFF_BF);
  float* bqk      = ws + OFF_BQK;
  float* bvo      = ws + OFF_BVO;
  float* wqbk     = ws + OFF_WQBK;
  float* c0       = ws + OFF_C0;
  float* Wqk      = ws + OFF_WQK;
  float* Wvo      = ws + OFF_WVO;
  float* qb       = ws + OFF_QB;
  int*   sorted   = (int*)(ws + OFF_SORTED);
  int*   srcs     = (int*)(ws + OFF_SRCS);
  float* sw       = ws + OFF_SW;
  float* p        = ws + OFF_P;   // [N,128]
  float* agg      = ws + OFF_P;   // aliased (ownership-safe)

  hipMemsetAsync(d_ws, 0, (size_t)ZERO_ELEMS * 4, stream);

  k_pre_count<<<129 + EDGE_BLKS, 256, 0, stream>>>(
      Wq, bq, Wk, bk, Wv, bv, Wo, ei, node_cnt, Wqk, bqk, Wvo, bvo, wqbk, c0);
  k_p<<<(NN + 63) / 64, 256, 0, stream>>>(nf, Wqk, bqk, wqbk, c0, p, qb);
  k_scan1<<<196, 256, 0, stream>>>(node_cnt, partial);
  k_scan2<<<1, 256, 0, stream>>>(partial);
  k_scan3<<<196, 256, 0, stream>>>(node_cnt, partial, node_off);
  k_scatter<<<EDGE_BLKS + BS_BLKS, 256, 0, stream>>>(ei, node_off, fill, sorted,
                                                     srcs, blockFirst);
  k_fused3<<<NWIN, 256, 0, stream>>>(tf, sorted, srcs, node_off, node_cnt,
                                     blockFirst, ce, p, qb, maskArr, agg, sw);
  k_out<<<(NN + 63) / 64, 256, 0, stream>>>(agg, Wvo, bvo, sw, bo, maskArr, out);
}